// Round 3
// baseline (418.970 us; speedup 1.0000x reference)
//
#include <hip/hip_runtime.h>
#include <hip/hip_bf16.h>

namespace {

constexpr int E_DIM = 512;
constexpr int NH = 8;
constexpr int HD = 64;
constexpr int LQ = 1024;
constexpr int LKV = 4096;
constexpr int NB = 4;
constexpr int SPLIT = 4;           // kv splits in attn_main
constexpr int SLICE = LKV / SPLIT; // 1024
constexpr int SSPLIT = 8;          // kv splits in attn_sums

typedef __attribute__((ext_vector_type(8))) short bf16x8;
typedef __attribute__((ext_vector_type(8))) unsigned short u16x8;
typedef __attribute__((ext_vector_type(4))) float f32x4;

__device__ __forceinline__ f32x4 mfma16(bf16x8 a, bf16x8 b, f32x4 c) {
  return __builtin_amdgcn_mfma_f32_16x16x32_bf16(a, b, c, 0, 0, 0);
}

// f32 -> bf16 bits, round-to-nearest-even (finite inputs only)
__device__ __forceinline__ unsigned short f2b(float f) {
  unsigned int u = __float_as_uint(f);
  u += 0x7FFFu + ((u >> 16) & 1u);
  return (unsigned short)(u >> 16);
}

__device__ __forceinline__ float b2f(short s) {
  return __uint_as_float(((unsigned int)(unsigned short)s) << 16);
}

// pack 2 f32 -> 2 bf16 in one u32 (low = a, high = b)
__device__ __forceinline__ unsigned int cvt_pk_bf16(float a, float b) {
  unsigned int r;
  asm("v_cvt_pk_bf16_f32 %0, %1, %2" : "=v"(r) : "v"(a), "v"(b));
  return r;
}

// out[i,j] = (sum_k X[i,k]*W[j,k] + bias[j]) * oscale   (N = K = 512)
// EPI 0: bf16 head-split  out[((b*NH+h)*L + l)*64 + d]
// EPI 1: bf16 head-split transposed  out[((b*NH+h)*64 + d)*L + l]
// EPI 2: f32 plain  out[i*512 + j]
template <int EPI>
__global__ __launch_bounds__(256) void gemm_proj(
    const float* __restrict__ X, const float* __restrict__ Wm,
    const float* __restrict__ bias, void* __restrict__ outp, int M, int L,
    float oscale) {
  __shared__ unsigned short As[64][40];
  __shared__ unsigned short Bs[64][40];
  const int tid = threadIdx.x;
  const int wv = tid >> 6, lane = tid & 63, lg = lane >> 4, lr = lane & 15;
  const int i0 = blockIdx.y * 64, j0 = blockIdx.x * 64;
  const int wr = (wv >> 1) * 32, wc = (wv & 1) * 32;
  const int srow = tid >> 2, scol = (tid & 3) * 8;
  f32x4 acc[2][2] = {};
  const float* xp = X + (size_t)(i0 + srow) * E_DIM + scol;
  const float* wp = Wm + (size_t)(j0 + srow) * E_DIM + scol;
  for (int k0 = 0; k0 < E_DIM; k0 += 32) {
    float4 a1 = *(const float4*)(xp + k0);
    float4 a2 = *(const float4*)(xp + k0 + 4);
    float4 b1 = *(const float4*)(wp + k0);
    float4 b2 = *(const float4*)(wp + k0 + 4);
    __syncthreads();
    u16x8 av, bv;
    av[0] = f2b(a1.x); av[1] = f2b(a1.y); av[2] = f2b(a1.z); av[3] = f2b(a1.w);
    av[4] = f2b(a2.x); av[5] = f2b(a2.y); av[6] = f2b(a2.z); av[7] = f2b(a2.w);
    bv[0] = f2b(b1.x); bv[1] = f2b(b1.y); bv[2] = f2b(b1.z); bv[3] = f2b(b1.w);
    bv[4] = f2b(b2.x); bv[5] = f2b(b2.y); bv[6] = f2b(b2.z); bv[7] = f2b(b2.w);
    *(u16x8*)&As[srow][scol] = av;
    *(u16x8*)&Bs[srow][scol] = bv;
    __syncthreads();
    bf16x8 af0 = *(const bf16x8*)&As[wr + lr][lg * 8];
    bf16x8 af1 = *(const bf16x8*)&As[wr + 16 + lr][lg * 8];
    bf16x8 bg0 = *(const bf16x8*)&Bs[wc + lr][lg * 8];
    bf16x8 bg1 = *(const bf16x8*)&Bs[wc + 16 + lr][lg * 8];
    acc[0][0] = mfma16(af0, bg0, acc[0][0]);
    acc[0][1] = mfma16(af0, bg1, acc[0][1]);
    acc[1][0] = mfma16(af1, bg0, acc[1][0]);
    acc[1][1] = mfma16(af1, bg1, acc[1][1]);
  }
  for (int mi = 0; mi < 2; ++mi)
    for (int ni = 0; ni < 2; ++ni) {
      const int j = j0 + wc + ni * 16 + lr;
      const float bj = bias[j];
      for (int r = 0; r < 4; ++r) {
        const int i = i0 + wr + mi * 16 + lg * 4 + r;
        const float v = (acc[mi][ni][r] + bj) * oscale;
        if (EPI == 2) {
          ((float*)outp)[(size_t)i * E_DIM + j] = v;
        } else {
          const int bb = i / L, li = i - bb * L;
          const int hh = j >> 6, dd = j & 63;
          if (EPI == 0)
            ((unsigned short*)outp)[((size_t)(bb * NH + hh) * L + li) * HD + dd] = f2b(v);
          else
            ((unsigned short*)outp)[((size_t)(bb * NH + hh) * HD + dd) * L + li] = f2b(v);
        }
      }
    }
}

// Pass 1: l[b,h,q] = sum_kv 2^(score2). Q pre-scaled by 0.125*log2(e).
// grid (LQ/64, NB, SSPLIT), 512 thr; wave = head; swapped mfma(K,Q).
__global__ __launch_bounds__(512, 4) void attn_sums(
    const unsigned short* __restrict__ Qb, const unsigned short* __restrict__ Kb,
    float* __restrict__ l_arr) {
  const int tid = threadIdx.x;
  const int h = tid >> 6, lane = tid & 63, lg = lane >> 4, lr = lane & 15;
  const int q0 = blockIdx.x * 64, b = blockIdx.y, sp = blockIdx.z;
  const size_t bh = (size_t)b * NH + h;
  const unsigned short* Qp = Qb + (bh * LQ + q0) * HD;
  const unsigned short* Kp = Kb + (bh * LKV + sp * (LKV / SSPLIT)) * HD;
  bf16x8 qB[4][2];
  for (int qs = 0; qs < 4; ++qs)
    for (int kk = 0; kk < 2; ++kk)
      qB[qs][kk] = *(const bf16x8*)(Qp + (qs * 16 + lr) * HD + kk * 32 + lg * 8);
  float qsum[4] = {};
  for (int t = 0; t < (LKV / SSPLIT) / 64; ++t) {
    const unsigned short* base = Kp + (size_t)t * 64 * HD;
    for (int k2h = 0; k2h < 2; ++k2h) {
      bf16x8 kA[2][2];
      for (int k2 = 0; k2 < 2; ++k2)
        for (int kk = 0; kk < 2; ++kk)
          kA[k2][kk] = *(const bf16x8*)(base + ((k2h * 2 + k2) * 16 + lr) * HD +
                                        kk * 32 + lg * 8);
      f32x4 sacc[2][4] = {};
      for (int k2 = 0; k2 < 2; ++k2)
        for (int qs = 0; qs < 4; ++qs)
          sacc[k2][qs] = mfma16(kA[k2][1], qB[qs][1],
                                mfma16(kA[k2][0], qB[qs][0], sacc[k2][qs]));
      for (int k2 = 0; k2 < 2; ++k2)
        for (int qs = 0; qs < 4; ++qs)
          for (int r = 0; r < 4; ++r)
            qsum[qs] += __builtin_amdgcn_exp2f(sacc[k2][qs][r]);
    }
  }
  for (int qs = 0; qs < 4; ++qs) {
    float v = qsum[qs];
    v += __shfl_xor(v, 16);
    v += __shfl_xor(v, 32);
    if (lg == 0) atomicAdd(&l_arr[bh * LQ + q0 + qs * 16 + lr], v);
  }
}

// Pass 2: swapped QK^T, exp2 with folded -log2(l), packed b64 P writes into
// XOR-swizzled double-buffered LDS, PV, head-avg attn_w. One barrier/tile.
// grid (LQ/64, NB, SPLIT), 512 thr; wave = head.
__global__ __launch_bounds__(512, 2) void attn_main(
    const unsigned short* __restrict__ Qb, const unsigned short* __restrict__ Kb,
    const unsigned short* __restrict__ Vt, const float* __restrict__ l_arr,
    float* __restrict__ attn_w, float* __restrict__ ctxp) {
  __shared__ __align__(16) unsigned short P[2][NH][64][64];  // 128 KB
  const int tid = threadIdx.x;
  const int h = tid >> 6, lane = tid & 63, lg = lane >> 4, lr = lane & 15;
  const int q0 = blockIdx.x * 64, b = blockIdx.y, sp = blockIdx.z;
  const size_t bh = (size_t)b * NH + h;
  const unsigned short* Qp = Qb + (bh * LQ + q0) * HD;
  const unsigned short* Kp = Kb + bh * LKV * HD;
  const unsigned short* Vp = Vt + bh * HD * LKV;

  bf16x8 qB[4][2];
  for (int qs = 0; qs < 4; ++qs)
    for (int kk = 0; kk < 2; ++kk)
      qB[qs][kk] = *(const bf16x8*)(Qp + (qs * 16 + lr) * HD + kk * 32 + lg * 8);
  // this lane's q-rows are q = qs*16 + lr; fold -log2(l) into the exponent
  float nlg[4];
  for (int qs = 0; qs < 4; ++qs)
    nlg[qs] = -__builtin_amdgcn_logf(l_arr[bh * LQ + q0 + qs * 16 + lr]);

  f32x4 cacc[4][4] = {};
  for (int t = 0; t < SLICE / 64; ++t) {
    const int kv0 = sp * SLICE + t * 64;
    unsigned short (*Pb)[64][64] = P[t & 1];
    // prefetch V fragments (used in PV below)
    bf16x8 vf[4][2];
    for (int ds = 0; ds < 4; ++ds)
      for (int kk = 0; kk < 2; ++kk)
        vf[ds][kk] = *(const bf16x8*)(Vp + (size_t)(ds * 16 + lr) * LKV + kv0 +
                                      kk * 32 + lg * 8);
    bf16x8 kA[4][2];
    for (int ks = 0; ks < 4; ++ks)
      for (int kk = 0; kk < 2; ++kk)
        kA[ks][kk] = *(const bf16x8*)(Kp + (size_t)(kv0 + ks * 16 + lr) * HD +
                                      kk * 32 + lg * 8);
    f32x4 sacc[4][4] = {};  // [ks][qs]: D[kv=ks*16+lg*4+r][q=qs*16+lr]
    for (int ks = 0; ks < 4; ++ks)
      for (int qs = 0; qs < 4; ++qs)
        sacc[ks][qs] = mfma16(kA[ks][1], qB[qs][1],
                              mfma16(kA[ks][0], qB[qs][0], sacc[ks][qs]));
    // normalized P = 2^(s + nlg), packed pairs, b64 swizzled writes
    for (int ks = 0; ks < 4; ++ks)
      for (int qs = 0; qs < 4; ++qs) {
        const int q = qs * 16 + lr;
        const float p0 = __builtin_amdgcn_exp2f(sacc[ks][qs][0] + nlg[qs]);
        const float p1 = __builtin_amdgcn_exp2f(sacc[ks][qs][1] + nlg[qs]);
        const float p2 = __builtin_amdgcn_exp2f(sacc[ks][qs][2] + nlg[qs]);
        const float p3 = __builtin_amdgcn_exp2f(sacc[ks][qs][3] + nlg[qs]);
        uint2 w;
        w.x = cvt_pk_bf16(p0, p1);
        w.y = cvt_pk_bf16(p2, p3);
        const int off = (ks * 16 + lg * 4) ^ ((q & 3) << 3);
        *(uint2*)&Pb[h][q][off] = w;
      }
    // PV on own head's P (in-wave LDS dependency; no barrier needed)
    for (int kk = 0; kk < 2; ++kk) {
      bf16x8 pa[4];
      for (int qs = 0; qs < 4; ++qs) {
        const int q = qs * 16 + lr;
        pa[qs] = *(const bf16x8*)&Pb[h][q][(kk * 32 + lg * 8) ^ ((q & 3) << 3)];
      }
      for (int qs = 0; qs < 4; ++qs)
        for (int ds = 0; ds < 4; ++ds)
          cacc[qs][ds] = mfma16(pa[qs], vf[ds][kk], cacc[qs][ds]);
    }
    __syncthreads();  // all heads' P visible for the average
    {
      const int qa = tid >> 3, La = tid & 7;
      const int off = (La * 8) ^ ((qa & 3) << 3);
      float s[8] = {};
      for (int hh = 0; hh < NH; ++hh) {
        const bf16x8 v = *(const bf16x8*)&Pb[hh][qa][off];
        for (int j = 0; j < 8; ++j) s[j] += b2f(v[j]);
      }
      float* op = attn_w + (size_t)(b * LQ + q0 + qa) * LKV + kv0 + La * 8;
      float4 o0 = {s[0] * 0.125f, s[1] * 0.125f, s[2] * 0.125f, s[3] * 0.125f};
      float4 o1 = {s[4] * 0.125f, s[5] * 0.125f, s[6] * 0.125f, s[7] * 0.125f};
      *(float4*)op = o0;
      *(float4*)(op + 4) = o1;
    }
    // no second barrier: next tile writes the other P buffer
  }
  float* cp = ctxp + (size_t)sp * ((size_t)NB * LQ * E_DIM);
  for (int qs = 0; qs < 4; ++qs)
    for (int ds = 0; ds < 4; ++ds)
      for (int r = 0; r < 4; ++r)
        cp[(size_t)(b * LQ + q0 + qs * 16 + lg * 4 + r) * E_DIM + h * HD +
           ds * 16 + lr] = cacc[qs][ds][r];
}

// ctxp[0] += ctxp[1..3]  (in place into plane 0)
__global__ __launch_bounds__(256) void combine_ctx(float* __restrict__ ctxp) {
  const size_t i = ((size_t)blockIdx.x * 256 + threadIdx.x) * 4;
  constexpr size_t PL = (size_t)NB * LQ * E_DIM;
  float4 a = *(float4*)(ctxp + i);
  float4 b = *(float4*)(ctxp + PL + i);
  float4 c = *(float4*)(ctxp + 2 * PL + i);
  float4 d = *(float4*)(ctxp + 3 * PL + i);
  float4 o = {a.x + b.x + c.x + d.x, a.y + b.y + c.y + d.y,
              a.z + b.z + c.z + d.z, a.w + b.w + c.w + d.w};
  *(float4*)(ctxp + i) = o;
}

// out = LN(query + attn_out) * gamma + beta ; one block per row
__global__ __launch_bounds__(256) void ln_kernel(
    const float* __restrict__ q, const float* __restrict__ ao,
    const float* __restrict__ gamma, const float* __restrict__ beta,
    float* __restrict__ out) {
  const int row = blockIdx.x;
  const int tid = threadIdx.x;
  const size_t base = (size_t)row * E_DIM;
  const float x0 = q[base + tid] + ao[base + tid];
  const float x1 = q[base + 256 + tid] + ao[base + 256 + tid];
  float s = x0 + x1, ss = x0 * x0 + x1 * x1;
  for (int off = 32; off >= 1; off >>= 1) {
    s += __shfl_down(s, off);
    ss += __shfl_down(ss, off);
  }
  __shared__ float ps[4], pss[4];
  if ((tid & 63) == 0) {
    ps[tid >> 6] = s;
    pss[tid >> 6] = ss;
  }
  __syncthreads();
  s = ps[0] + ps[1] + ps[2] + ps[3];
  ss = pss[0] + pss[1] + pss[2] + pss[3];
  const float mu = s * (1.f / E_DIM);
  float var = ss * (1.f / E_DIM) - mu * mu;
  var = fmaxf(var, 0.f);
  const float rstd = rsqrtf(var + 1e-5f);
  out[base + tid] = (x0 - mu) * rstd * gamma[tid] + beta[tid];
  out[base + 256 + tid] = (x1 - mu) * rstd * gamma[256 + tid] + beta[256 + tid];
}

}  // namespace

extern "C" void kernel_launch(void* const* d_in, const int* in_sizes, int n_in,
                              void* d_out, int out_size, void* d_ws, size_t ws_size,
                              hipStream_t stream) {
  const float* query = (const float*)d_in[0];
  const float* key_value = (const float*)d_in[1];
  const float* w_q = (const float*)d_in[2];
  const float* w_k = (const float*)d_in[3];
  const float* w_v = (const float*)d_in[4];
  const float* b_q = (const float*)d_in[5];
  const float* b_k = (const float*)d_in[6];
  const float* b_v = (const float*)d_in[7];
  const float* w_o = (const float*)d_in[8];
  const float* b_o = (const float*)d_in[9];
  const float* ln_g = (const float*)d_in[10];
  const float* ln_b = (const float*)d_in[11];

  // ws: Qb 4MB | Kb 16MB | Vt 16MB | l 128KB | ctxp 4x8MB | ao 8MB  (~76 MB)
  unsigned short* Qb = (unsigned short*)d_ws;
  unsigned short* Kb = Qb + (size_t)NB * NH * LQ * HD;
  unsigned short* Vt = Kb + (size_t)NB * NH * LKV * HD;
  float* l_arr = (float*)(Vt + (size_t)NB * NH * LKV * HD);
  float* ctxp = l_arr + (size_t)NB * NH * LQ;
  float* ao = ctxp + (size_t)SPLIT * NB * LQ * E_DIM;

  float* out = (float*)d_out;
  float* attn_w = out + (size_t)NB * LQ * E_DIM;

  hipMemsetAsync(l_arr, 0, sizeof(float) * NB * NH * LQ, stream);

  dim3 blk(256);
  // Q projection folds in 1/sqrt(64) * log2(e) so scores are in log2 space.
  const float qscale = 0.125f * 1.44269504088896340736f;
  gemm_proj<0><<<dim3(8, (NB * LQ) / 64), blk, 0, stream>>>(query, w_q, b_q, Qb,
                                                            NB * LQ, LQ, qscale);
  gemm_proj<0><<<dim3(8, (NB * LKV) / 64), blk, 0, stream>>>(key_value, w_k, b_k,
                                                             Kb, NB * LKV, LKV, 1.0f);
  gemm_proj<1><<<dim3(8, (NB * LKV) / 64), blk, 0, stream>>>(key_value, w_v, b_v,
                                                             Vt, NB * LKV, LKV, 1.0f);
  attn_sums<<<dim3(LQ / 64, NB, SSPLIT), dim3(512), 0, stream>>>(Qb, Kb, l_arr);
  attn_main<<<dim3(LQ / 64, NB, SPLIT), dim3(512), 0, stream>>>(Qb, Kb, Vt, l_arr,
                                                                attn_w, ctxp);
  combine_ctx<<<dim3((NB * LQ * E_DIM) / (256 * 4)), blk, 0, stream>>>(ctxp);
  gemm_proj<2><<<dim3(8, (NB * LQ) / 64), blk, 0, stream>>>(ctxp, w_o, b_o, ao,
                                                            NB * LQ, LQ, 1.0f);
  ln_kernel<<<dim3(NB * LQ), blk, 0, stream>>>(query, ao, ln_g, ln_b, out);
}

// Round 4
// 257.048 us; speedup vs baseline: 1.6299x; 1.6299x over previous
//
#include <hip/hip_runtime.h>
#include <hip/hip_bf16.h>

namespace {

constexpr int E_DIM = 512;
constexpr int NH = 8;
constexpr int HD = 64;
constexpr int LQ = 1024;
constexpr int LKV = 4096;
constexpr int NB = 4;
constexpr int SPLIT = 4;           // kv splits in attn_main
constexpr int SLICE = LKV / SPLIT; // 1024
constexpr int SSPLIT = 8;          // kv splits in attn_sums
constexpr size_t CPL = (size_t)NB * LQ * E_DIM;  // ctx plane elems

typedef __attribute__((ext_vector_type(8))) short bf16x8;
typedef __attribute__((ext_vector_type(8))) unsigned short u16x8;
typedef __attribute__((ext_vector_type(4))) float f32x4;

typedef const unsigned int __attribute__((address_space(1)))* gptr1;
typedef unsigned int __attribute__((address_space(3)))* lptr3;

__device__ __forceinline__ void gl16(const unsigned short* g, unsigned short* l) {
  __builtin_amdgcn_global_load_lds((gptr1)g, (lptr3)l, 16, 0, 0);
}

__device__ __forceinline__ f32x4 mfma16(bf16x8 a, bf16x8 b, f32x4 c) {
  return __builtin_amdgcn_mfma_f32_16x16x32_bf16(a, b, c, 0, 0, 0);
}

// f32 -> bf16 bits, round-to-nearest-even (finite inputs only)
__device__ __forceinline__ unsigned short f2b(float f) {
  unsigned int u = __float_as_uint(f);
  u += 0x7FFFu + ((u >> 16) & 1u);
  return (unsigned short)(u >> 16);
}

__device__ __forceinline__ float b2f(short s) {
  return __uint_as_float(((unsigned int)(unsigned short)s) << 16);
}

__device__ __forceinline__ unsigned int cvt_pk_bf16(float a, float b) {
  unsigned int r;
  asm("v_cvt_pk_bf16_f32 %0, %1, %2" : "=v"(r) : "v"(a), "v"(b));
  return r;
}

// ---- f32 -> bf16 converters -------------------------------------------------
__global__ __launch_bounds__(256) void cvt_bf16(const float* __restrict__ s,
                                                unsigned short* __restrict__ d) {
  const int i = blockIdx.x * 256 + threadIdx.x;  // 8 elems per thread
  const float4 a = ((const float4*)s)[i * 2];
  const float4 b = ((const float4*)s)[i * 2 + 1];
  uint4 o;
  o.x = cvt_pk_bf16(a.x, a.y);
  o.y = cvt_pk_bf16(a.z, a.w);
  o.z = cvt_pk_bf16(b.x, b.y);
  o.w = cvt_pk_bf16(b.z, b.w);
  ((uint4*)d)[i] = o;
}

__global__ __launch_bounds__(256) void cvt_w4(const float* __restrict__ w0,
                                              const float* __restrict__ w1,
                                              const float* __restrict__ w2,
                                              const float* __restrict__ w3,
                                              unsigned short* __restrict__ d) {
  const float* s = blockIdx.y == 0 ? w0 : blockIdx.y == 1 ? w1
                   : blockIdx.y == 2 ? w2 : w3;
  unsigned short* dst = d + (size_t)blockIdx.y * (E_DIM * E_DIM);
  const int i = blockIdx.x * 256 + threadIdx.x;
  const float4 a = ((const float4*)s)[i * 2];
  const float4 b = ((const float4*)s)[i * 2 + 1];
  uint4 o;
  o.x = cvt_pk_bf16(a.x, a.y);
  o.y = cvt_pk_bf16(a.z, a.w);
  o.z = cvt_pk_bf16(b.x, b.y);
  o.w = cvt_pk_bf16(b.z, b.w);
  ((uint4*)dst)[i] = o;
}

// ---- bf16 GEMM, 128x128 tile, BK=32, global_load_lds staging ---------------
// out[i,j] = (sum_k A[i,k]*B[j,k] + bias[j]) * oscale, K=N=512
// EPI 0: bf16 head-split; EPI 1: bf16 head-split transposed; EPI 2: f32 plain
template <int EPI>
__global__ __launch_bounds__(256) void gemm_bf16(
    const unsigned short* __restrict__ A, const unsigned short* __restrict__ B,
    const float* __restrict__ bias, void* __restrict__ outp, int L,
    float oscale) {
  __shared__ __align__(16) unsigned short As[128][32];
  __shared__ __align__(16) unsigned short Bs[128][32];
  const int tid = threadIdx.x;
  const int wv = tid >> 6, lane = tid & 63, lg = lane >> 4, lr = lane & 15;
  // XCD remap: same-row-panel blocks (same by) co-locate on one XCD
  const int gx = gridDim.x, gy = gridDim.y;
  const int p = blockIdx.x + gx * blockIdx.y;
  const int xcd = p & 7, ii = p >> 3;
  const int by = xcd * (gy >> 3) + ii / gx;
  const int bx = ii - (ii / gx) * gx;
  const int i0 = by * 128, j0 = bx * 128;
  const int wm = wv >> 1, wn = wv & 1;
  const int srow = tid >> 2, scol = (tid & 3) * 8;
  f32x4 acc[4][4] = {};
  const unsigned short* ap = A + (size_t)(i0 + srow) * E_DIM + scol;
  const unsigned short* bp = B + (size_t)(j0 + srow) * E_DIM + scol;
  unsigned short* lA = &As[srow][scol];
  unsigned short* lB = &Bs[srow][scol];
  for (int k0 = 0; k0 < E_DIM; k0 += 32) {
    __syncthreads();  // previous iteration's ds_reads done
    gl16(ap + k0, lA);
    gl16(ap + k0 + (size_t)64 * E_DIM, lA + 64 * 32);
    gl16(bp + k0, lB);
    gl16(bp + k0 + (size_t)64 * E_DIM, lB + 64 * 32);
    __syncthreads();  // drains vmcnt before barrier
    bf16x8 af[4], bg[4];
    for (int m = 0; m < 4; ++m)
      af[m] = *(const bf16x8*)&As[wm * 64 + m * 16 + lr][lg * 8];
    for (int n = 0; n < 4; ++n)
      bg[n] = *(const bf16x8*)&Bs[wn * 64 + n * 16 + lr][lg * 8];
    for (int m = 0; m < 4; ++m)
      for (int n = 0; n < 4; ++n)
        acc[m][n] = mfma16(af[m], bg[n], acc[m][n]);
  }
  for (int m = 0; m < 4; ++m)
    for (int n = 0; n < 4; ++n) {
      const int j = j0 + wn * 64 + n * 16 + lr;
      const float bj = bias[j];
      for (int r = 0; r < 4; ++r) {
        const int i = i0 + wm * 64 + m * 16 + lg * 4 + r;
        const float v = (acc[m][n][r] + bj) * oscale;
        if (EPI == 2) {
          ((float*)outp)[(size_t)i * E_DIM + j] = v;
        } else {
          const int bb = i / L, li = i - bb * L;
          const int hh = j >> 6, dd = j & 63;
          if (EPI == 0)
            ((unsigned short*)outp)[((size_t)(bb * NH + hh) * L + li) * HD + dd] = f2b(v);
          else
            ((unsigned short*)outp)[((size_t)(bb * NH + hh) * HD + dd) * L + li] = f2b(v);
        }
      }
    }
}

// ---- Pass 1: l_part[sp][b,h,q] = sum over kv slice of 2^score ---------------
// grid (16, NB, SSPLIT) remapped so same (b,sp) shares an XCD. wave = head.
__global__ __launch_bounds__(512, 2) void attn_sums(
    const unsigned short* __restrict__ Qb, const unsigned short* __restrict__ Kb,
    float* __restrict__ l_part) {
  const int tid = threadIdx.x;
  const int h = tid >> 6, lane = tid & 63, lg = lane >> 4, lr = lane & 15;
  const int p = blockIdx.x + 16 * blockIdx.y + 64 * blockIdx.z;
  const int xcd = p & 7, ii = p >> 3;
  const int combo = xcd * 4 + (ii >> 4);
  const int q0 = (ii & 15) * 64;
  const int b = combo >> 3, sp = combo & 7;
  const size_t bh = (size_t)b * NH + h;
  const unsigned short* Qp = Qb + (bh * LQ + q0) * HD;
  const unsigned short* Kp = Kb + (bh * LKV + sp * (LKV / SSPLIT)) * HD;
  bf16x8 qB[4][2];
  for (int qs = 0; qs < 4; ++qs)
    for (int kk = 0; kk < 2; ++kk)
      qB[qs][kk] = *(const bf16x8*)(Qp + (qs * 16 + lr) * HD + kk * 32 + lg * 8);
  float qsum[4] = {};
  for (int t = 0; t < (LKV / SSPLIT) / 64; ++t) {
    const unsigned short* base = Kp + (size_t)t * 64 * HD;
    for (int k2h = 0; k2h < 2; ++k2h) {
      bf16x8 kA[2][2];
      for (int k2 = 0; k2 < 2; ++k2)
        for (int kk = 0; kk < 2; ++kk)
          kA[k2][kk] = *(const bf16x8*)(base + ((k2h * 2 + k2) * 16 + lr) * HD +
                                        kk * 32 + lg * 8);
      f32x4 sacc[2][4] = {};
      for (int k2 = 0; k2 < 2; ++k2)
        for (int qs = 0; qs < 4; ++qs)
          sacc[k2][qs] = mfma16(kA[k2][1], qB[qs][1],
                                mfma16(kA[k2][0], qB[qs][0], sacc[k2][qs]));
      for (int k2 = 0; k2 < 2; ++k2)
        for (int qs = 0; qs < 4; ++qs)
          for (int r = 0; r < 4; ++r)
            qsum[qs] += __builtin_amdgcn_exp2f(sacc[k2][qs][r]);
    }
  }
  for (int qs = 0; qs < 4; ++qs) {
    float v = qsum[qs];
    v += __shfl_xor(v, 16);
    v += __shfl_xor(v, 32);
    if (lg == 0)
      l_part[(size_t)sp * (NB * NH * LQ) + bh * LQ + q0 + qs * 16 + lr] = v;
  }
}

// ---- Pass 2: P (bf16, pitch-72 LDS, double-buffered), PV, head-avg ----------
// grid (16, NB, SPLIT) remapped so same (b,sp) shares an XCD. wave = head.
__global__ __launch_bounds__(512) void attn_main(
    const unsigned short* __restrict__ Qb, const unsigned short* __restrict__ Kb,
    const unsigned short* __restrict__ Vt, const float* __restrict__ l_part,
    float* __restrict__ attn_w, unsigned short* __restrict__ ctxp) {
  __shared__ __align__(16) unsigned short P[2][NH][64][72];  // 144 KB
  const int tid = threadIdx.x;
  const int h = tid >> 6, lane = tid & 63, lg = lane >> 4, lr = lane & 15;
  const int p = blockIdx.x + 16 * blockIdx.y + 64 * blockIdx.z;
  const int xcd = p & 7, ii = p >> 3;
  const int combo = xcd * 2 + (ii >> 4);
  const int q0 = (ii & 15) * 64;
  const int b = combo >> 2, sp = combo & 3;
  const size_t bh = (size_t)b * NH + h;
  const unsigned short* Qp = Qb + (bh * LQ + q0) * HD;
  const unsigned short* Kp = Kb + bh * LKV * HD;
  const unsigned short* Vp = Vt + bh * HD * LKV;

  bf16x8 qB[4][2];
  for (int qs = 0; qs < 4; ++qs)
    for (int kk = 0; kk < 2; ++kk)
      qB[qs][kk] = *(const bf16x8*)(Qp + (qs * 16 + lr) * HD + kk * 32 + lg * 8);
  float nlg[4];
  for (int qs = 0; qs < 4; ++qs) {
    float ls = 0.f;
    for (int s = 0; s < SSPLIT; ++s)
      ls += l_part[(size_t)s * (NB * NH * LQ) + bh * LQ + q0 + qs * 16 + lr];
    nlg[qs] = -__builtin_amdgcn_logf(ls);
  }

  f32x4 cacc[4][4] = {};
  for (int t = 0; t < SLICE / 64; ++t) {
    const int kv0 = sp * SLICE + t * 64;
    unsigned short (*Pb)[64][72] = P[t & 1];
    bf16x8 vf[4][2];
    for (int ds = 0; ds < 4; ++ds)
      for (int kk = 0; kk < 2; ++kk)
        vf[ds][kk] = *(const bf16x8*)(Vp + (size_t)(ds * 16 + lr) * LKV + kv0 +
                                      kk * 32 + lg * 8);
    for (int kh = 0; kh < 2; ++kh) {
      bf16x8 kA[2][2];
      for (int k2 = 0; k2 < 2; ++k2)
        for (int kk = 0; kk < 2; ++kk)
          kA[k2][kk] = *(const bf16x8*)(Kp + (size_t)(kv0 + (kh * 2 + k2) * 16 + lr) * HD +
                                        kk * 32 + lg * 8);
      f32x4 sacc[2][4] = {};
      for (int k2 = 0; k2 < 2; ++k2)
        for (int qs = 0; qs < 4; ++qs)
          sacc[k2][qs] = mfma16(kA[k2][1], qB[qs][1],
                                mfma16(kA[k2][0], qB[qs][0], sacc[k2][qs]));
      for (int k2 = 0; k2 < 2; ++k2)
        for (int qs = 0; qs < 4; ++qs) {
          const int q = qs * 16 + lr;
          const float p0 = __builtin_amdgcn_exp2f(sacc[k2][qs][0] + nlg[qs]);
          const float p1 = __builtin_amdgcn_exp2f(sacc[k2][qs][1] + nlg[qs]);
          const float p2 = __builtin_amdgcn_exp2f(sacc[k2][qs][2] + nlg[qs]);
          const float p3 = __builtin_amdgcn_exp2f(sacc[k2][qs][3] + nlg[qs]);
          uint2 w;
          w.x = cvt_pk_bf16(p0, p1);
          w.y = cvt_pk_bf16(p2, p3);
          *(uint2*)&Pb[h][q][(kh * 2 + k2) * 16 + lg * 4] = w;
        }
    }
    // PV on own head's P (same-wave LDS dependency)
    for (int kk = 0; kk < 2; ++kk) {
      bf16x8 pa[4];
      for (int qs = 0; qs < 4; ++qs)
        pa[qs] = *(const bf16x8*)&Pb[h][qs * 16 + lr][kk * 32 + lg * 8];
      for (int qs = 0; qs < 4; ++qs)
        for (int ds = 0; ds < 4; ++ds)
          cacc[qs][ds] = mfma16(pa[qs], vf[ds][kk], cacc[qs][ds]);
    }
    __syncthreads();  // all heads' P visible
    {
      const int qa = tid >> 3, La = tid & 7;
      float s[8] = {};
      for (int hh = 0; hh < NH; ++hh) {
        const bf16x8 v = *(const bf16x8*)&Pb[hh][qa][La * 8];
        for (int j = 0; j < 8; ++j) s[j] += b2f(v[j]);
      }
      float* op = attn_w + (size_t)(b * LQ + q0 + qa) * LKV + kv0 + La * 8;
      float4 o0 = {s[0] * 0.125f, s[1] * 0.125f, s[2] * 0.125f, s[3] * 0.125f};
      float4 o1 = {s[4] * 0.125f, s[5] * 0.125f, s[6] * 0.125f, s[7] * 0.125f};
      *(float4*)op = o0;
      *(float4*)(op + 4) = o1;
    }
    // no second barrier: next tile writes the other P buffer
  }
  unsigned short* cp = ctxp + (size_t)sp * CPL;
  for (int qs = 0; qs < 4; ++qs)
    for (int ds = 0; ds < 4; ++ds)
      for (int r = 0; r < 4; ++r)
        cp[(size_t)(b * LQ + q0 + qs * 16 + lg * 4 + r) * E_DIM + h * HD +
           ds * 16 + lr] = f2b(cacc[qs][ds][r]);
}

// sum 4 bf16 ctx planes -> bf16 ctx
__global__ __launch_bounds__(256) void combine_ctx(
    const unsigned short* __restrict__ ctxp, unsigned short* __restrict__ ctxb) {
  const size_t i = (size_t)blockIdx.x * 256 + threadIdx.x;  // 8 elems
  float s[8] = {};
  for (int pl = 0; pl < SPLIT; ++pl) {
    const bf16x8 v = ((const bf16x8*)(ctxp + pl * CPL))[i];
    for (int j = 0; j < 8; ++j) s[j] += b2f(v[j]);
  }
  uint4 o;
  o.x = cvt_pk_bf16(s[0], s[1]);
  o.y = cvt_pk_bf16(s[2], s[3]);
  o.z = cvt_pk_bf16(s[4], s[5]);
  o.w = cvt_pk_bf16(s[6], s[7]);
  ((uint4*)ctxb)[i] = o;
}

// out = LN(query + attn_out) * gamma + beta ; one block per row
__global__ __launch_bounds__(256) void ln_kernel(
    const float* __restrict__ q, const float* __restrict__ ao,
    const float* __restrict__ gamma, const float* __restrict__ beta,
    float* __restrict__ out) {
  const int row = blockIdx.x;
  const int tid = threadIdx.x;
  const size_t base = (size_t)row * E_DIM;
  const float x0 = q[base + tid] + ao[base + tid];
  const float x1 = q[base + 256 + tid] + ao[base + 256 + tid];
  float s = x0 + x1, ss = x0 * x0 + x1 * x1;
  for (int off = 32; off >= 1; off >>= 1) {
    s += __shfl_down(s, off);
    ss += __shfl_down(ss, off);
  }
  __shared__ float ps[4], pss[4];
  if ((tid & 63) == 0) {
    ps[tid >> 6] = s;
    pss[tid >> 6] = ss;
  }
  __syncthreads();
  s = ps[0] + ps[1] + ps[2] + ps[3];
  ss = pss[0] + pss[1] + pss[2] + pss[3];
  const float mu = s * (1.f / E_DIM);
  float var = ss * (1.f / E_DIM) - mu * mu;
  var = fmaxf(var, 0.f);
  const float rstd = rsqrtf(var + 1e-5f);
  out[base + tid] = (x0 - mu) * rstd * gamma[tid] + beta[tid];
  out[base + 256 + tid] = (x1 - mu) * rstd * gamma[256 + tid] + beta[256 + tid];
}

}  // namespace

extern "C" void kernel_launch(void* const* d_in, const int* in_sizes, int n_in,
                              void* d_out, int out_size, void* d_ws, size_t ws_size,
                              hipStream_t stream) {
  const float* query = (const float*)d_in[0];
  const float* key_value = (const float*)d_in[1];
  const float* w_q = (const float*)d_in[2];
  const float* w_k = (const float*)d_in[3];
  const float* w_v = (const float*)d_in[4];
  const float* b_q = (const float*)d_in[5];
  const float* b_k = (const float*)d_in[6];
  const float* b_v = (const float*)d_in[7];
  const float* w_o = (const float*)d_in[8];
  const float* b_o = (const float*)d_in[9];
  const float* ln_g = (const float*)d_in[10];
  const float* ln_b = (const float*)d_in[11];

  // ws layout (bytes, ~67 MB total; aliases noted)
  unsigned short* Qb = (unsigned short*)d_ws;            // 2,097,152 u16
  unsigned short* Kb = Qb + 2097152;                     // 8,388,608 u16
  unsigned short* Vt = Kb + 8388608;                     // 8,388,608 u16
  float* l_part = (float*)(Vt + 8388608);                // 262,144 f32
  unsigned short* Wb = (unsigned short*)(l_part + 262144); // 1,048,576 u16
  float* ao = (float*)(Wb + 1048576);                    // 2,097,152 f32
  unsigned short* KVb = (unsigned short*)(ao + 2097152); // 8,388,608 u16
  unsigned short* ctxp = KVb;                            // alias (KVb dead)
  unsigned short* Qxb = KVb + 8388608;                   // 2,097,152 u16
  unsigned short* ctxb = Qxb;                            // alias (Qxb dead)

  float* out = (float*)d_out;
  float* attn_w = out + (size_t)NB * LQ * E_DIM;

  const float qscale = 0.125f * 1.44269504088896340736f;  // 1/sqrt(64)*log2(e)

  cvt_bf16<<<dim3(4096), dim3(256), 0, stream>>>(key_value, KVb);
  cvt_bf16<<<dim3(1024), dim3(256), 0, stream>>>(query, Qxb);
  cvt_w4<<<dim3(128, 4), dim3(256), 0, stream>>>(w_q, w_k, w_v, w_o, Wb);

  gemm_bf16<0><<<dim3(4, 32), dim3(256), 0, stream>>>(Qxb, Wb, b_q, Qb, LQ, qscale);
  gemm_bf16<0><<<dim3(4, 128), dim3(256), 0, stream>>>(KVb, Wb + 262144, b_k, Kb,
                                                       LKV, 1.0f);
  gemm_bf16<1><<<dim3(4, 128), dim3(256), 0, stream>>>(KVb, Wb + 524288, b_v, Vt,
                                                       LKV, 1.0f);

  attn_sums<<<dim3(16, NB, SSPLIT), dim3(512), 0, stream>>>(Qb, Kb, l_part);
  attn_main<<<dim3(16, NB, SPLIT), dim3(512), 0, stream>>>(Qb, Kb, Vt, l_part,
                                                           attn_w, ctxp);
  combine_ctx<<<dim3(1024), dim3(256), 0, stream>>>(ctxp, ctxb);
  gemm_bf16<2><<<dim3(4, 32), dim3(256), 0, stream>>>(ctxb, Wb + 786432, b_o, ao,
                                                      LQ, 1.0f);
  ln_kernel<<<dim3(NB * LQ), dim3(256), 0, stream>>>(query, ao, ln_g, ln_b, out);
}